// Round 1
// baseline (567.248 us; speedup 1.0000x reference)
//
#include <hip/hip_runtime.h>
#include <hip/hip_bf16.h>
#include <cstdint>

// CausalSelfAttention: x[4,2048,1024] @ w_qkv[1024,3072] -> causal attn (H=16, Dh=64) -> @ w_out[1024,1024]
// All heavy compute in bf16 MFMA (16x16x32), fp32 accumulate.
//
// Workspace layout (bytes):
//   xb    @ 0         : 8192*1024 bf16   (16,777,216)
//   wqkvT @ 16777216  : 3072*1024 bf16   ( 6,291,456)   w_qkv transposed to [N][K]
//   woutT @ 23068672  : 1024*1024 bf16   ( 2,097,152)   w_out  transposed to [N][K]
//   qkvb  @ 25165824  : 8192*3072 bf16   (50,331,648)
//   vtb   @ 75497472  : 4*16*64*2048 bf16(16,777,216)   V transposed to [B,H,Dh,T]
//   ctx   @ 92274688  : 8192*1024 bf16   (16,777,216)
// total ~104 MB

typedef __bf16 bf16x8 __attribute__((ext_vector_type(8)));
typedef __bf16 bf16x4 __attribute__((ext_vector_type(4)));
typedef float  f32x4  __attribute__((ext_vector_type(4)));

#define MFMA16(a, b, c) __builtin_amdgcn_mfma_f32_16x16x32_bf16((a), (b), (c), 0, 0, 0)

__device__ __forceinline__ void gload16(const void* g, void* lds) {
  // global -> LDS direct copy, 16B per lane; LDS dest = wave-uniform base + lane*16
  __builtin_amdgcn_global_load_lds(
      (const __attribute__((address_space(1))) void*)(uintptr_t)g,
      (__attribute__((address_space(3))) void*)(uint32_t)(uintptr_t)lds,
      16, 0, 0);
}

// ---------------- fp32 -> bf16 elementwise ----------------
__global__ __launch_bounds__(256) void k_f32_to_bf16(const float* __restrict__ in,
                                                     __bf16* __restrict__ out, int n) {
  int idx = (blockIdx.x * 256 + threadIdx.x) * 4;
  int stride = gridDim.x * 256 * 4;
  for (; idx < n; idx += stride) {
    float4 v = *(const float4*)(in + idx);
    bf16x4 o = { (__bf16)v.x, (__bf16)v.y, (__bf16)v.z, (__bf16)v.w };
    *(bf16x4*)(out + idx) = o;
  }
}

// ---------------- fp32 [R][C] -> bf16 [C][R] transpose ----------------
__global__ __launch_bounds__(256) void k_transpose_f32_bf16(const float* __restrict__ in,
                                                            __bf16* __restrict__ out,
                                                            int R, int C) {
  __shared__ float t[64][65];
  const int r0 = blockIdx.y * 64, c0 = blockIdx.x * 64;
  const int tx = threadIdx.x & 15, ty = threadIdx.x >> 4;
#pragma unroll
  for (int rr = 0; rr < 4; ++rr) {
    int r = ty + rr * 16;
    float4 v = *(const float4*)(in + (size_t)(r0 + r) * C + c0 + tx * 4);
    t[r][tx * 4 + 0] = v.x; t[r][tx * 4 + 1] = v.y;
    t[r][tx * 4 + 2] = v.z; t[r][tx * 4 + 3] = v.w;
  }
  __syncthreads();
#pragma unroll
  for (int rr = 0; rr < 4; ++rr) {
    int c = ty + rr * 16;
    bf16x4 o = { (__bf16)t[tx * 4 + 0][c], (__bf16)t[tx * 4 + 1][c],
                 (__bf16)t[tx * 4 + 2][c], (__bf16)t[tx * 4 + 3][c] };
    *(bf16x4*)(out + (size_t)(c0 + c) * R + r0 + tx * 4) = o;
  }
}

// ---------------- V slice of qkv -> [B,H,Dh,T] ----------------
__global__ __launch_bounds__(256) void k_vtrans(const __bf16* __restrict__ qkv,
                                                __bf16* __restrict__ vt) {
  __shared__ __bf16 t[64][72];
  const int t0 = blockIdx.x * 64, h = blockIdx.y, b = blockIdx.z;
  const int tx = threadIdx.x & 15, ty = threadIdx.x >> 4;
#pragma unroll
  for (int rr = 0; rr < 4; ++rr) {
    int tt = ty + rr * 16;
    bf16x4 v = *(const bf16x4*)(qkv + (size_t)(b * 2048 + t0 + tt) * 3072 + 2048 + h * 64 + tx * 4);
    t[tt][tx * 4 + 0] = v[0]; t[tt][tx * 4 + 1] = v[1];
    t[tt][tx * 4 + 2] = v[2]; t[tt][tx * 4 + 3] = v[3];
  }
  __syncthreads();
#pragma unroll
  for (int rr = 0; rr < 4; ++rr) {
    int d = ty + rr * 16;
    bf16x4 o = { t[tx * 4 + 0][d], t[tx * 4 + 1][d], t[tx * 4 + 2][d], t[tx * 4 + 3][d] };
    *(bf16x4*)(vt + ((size_t)((b * 16 + h) * 64 + d)) * 2048 + t0 + tx * 4) = o;
  }
}

// ---------------- GEMM: C[M][N] = A[M][K] * BT[N][K]^T  (bf16 in, OutT out) ----------------
// 128x128 tile, BK=32, 4 waves, m97 structure (global_load_lds width-16 staging).
template <typename OutT>
__global__ __launch_bounds__(256) void k_gemm_bt(const __bf16* __restrict__ A,
                                                 const __bf16* __restrict__ BT,
                                                 OutT* __restrict__ C,
                                                 int M, int N, int K) {
  __shared__ __align__(16) __bf16 At[128 * 32];
  __shared__ __align__(16) __bf16 Bt[128 * 32];
  const int tid = threadIdx.x;
  const int l = tid & 63, w = tid >> 6;
  const int wr = w >> 1, wc = w & 1;
  const int lr = l & 15, lk = l >> 4;
  const int bm0 = blockIdx.y * 128, bn0 = blockIdx.x * 128;

  // staging map: instr i covers LDS bytes [i*4096 + w*1024 + l*16)
  const int sm = w * 16 + (l >> 2);
  const int sk = (l & 3) * 8;
  const __bf16* ga0 = A + (size_t)(bm0 + sm) * K + sk;
  const __bf16* ga1 = A + (size_t)(bm0 + 64 + sm) * K + sk;
  const __bf16* gb0 = BT + (size_t)(bn0 + sm) * K + sk;
  const __bf16* gb1 = BT + (size_t)(bn0 + 64 + sm) * K + sk;
  char* lA = (char*)At + w * 1024;
  char* lB = (char*)Bt + w * 1024;

  const f32x4 fz = {0.f, 0.f, 0.f, 0.f};
  f32x4 acc[4][4];
#pragma unroll
  for (int i = 0; i < 4; ++i) {
#pragma unroll
    for (int j = 0; j < 4; ++j) acc[i][j] = fz;
  }

  for (int k0 = 0; k0 < K; k0 += 32) {
    gload16(ga0, lA);
    gload16(ga1, lA + 4096);
    gload16(gb0, lB);
    gload16(gb1, lB + 4096);
    ga0 += 32; ga1 += 32; gb0 += 32; gb1 += 32;
    __syncthreads();
    bf16x8 af[4], bfr[4];
#pragma unroll
    for (int i = 0; i < 4; ++i)
      af[i] = *(const bf16x8*)(At + (wr * 64 + i * 16 + lr) * 32 + lk * 8);
#pragma unroll
    for (int j = 0; j < 4; ++j)
      bfr[j] = *(const bf16x8*)(Bt + (wc * 64 + j * 16 + lr) * 32 + lk * 8);
#pragma unroll
    for (int i = 0; i < 4; ++i) {
#pragma unroll
      for (int j = 0; j < 4; ++j) acc[i][j] = MFMA16(af[i], bfr[j], acc[i][j]);
    }
    __syncthreads();
  }

#pragma unroll
  for (int i = 0; i < 4; ++i) {
#pragma unroll
    for (int j = 0; j < 4; ++j) {
#pragma unroll
      for (int jj = 0; jj < 4; ++jj) {
        int row = bm0 + wr * 64 + i * 16 + lk * 4 + jj;
        int col = bn0 + wc * 64 + j * 16 + lr;
        C[(size_t)row * N + col] = (OutT)acc[i][j][jj];
      }
    }
  }
}

// ---------------- causal flash attention ----------------
// grid (32 qtiles, 16 heads, 4 batch), 4 waves/block, each wave owns 16 q rows.
// KV tile = 64. Q,K read straight from qkv buffer; V from transposed vtb.
__global__ __launch_bounds__(256) void k_attn(const __bf16* __restrict__ qkv,
                                              const __bf16* __restrict__ vt,
                                              __bf16* __restrict__ ctx) {
  const int qt = blockIdx.x, h = blockIdx.y, b = blockIdx.z;
  const int l = threadIdx.x & 63, w = threadIdx.x >> 6;
  const int lr = l & 15, lk = l >> 4;
  const int q0 = qt * 64 + w * 16;

  __shared__ __align__(16) __bf16 plds[4][16][72];  // per-wave P tile, padded

  const __bf16* qp = qkv + (size_t)(b * 2048 + q0 + lr) * 3072 + h * 64 + lk * 8;
  bf16x8 aq0 = *(const bf16x8*)qp;
  bf16x8 aq1 = *(const bf16x8*)(qp + 32);
  const __bf16* kbase = qkv + (size_t)(b * 2048 + lr) * 3072 + 1024 + h * 64 + lk * 8;
  const __bf16* vbase = vt + (size_t)((b * 16 + h) * 64 + lr) * 2048 + lk * 8;

  const f32x4 fz = {0.f, 0.f, 0.f, 0.f};
  const float NEG = -1e30f;
  float m_run[4], lsum[4];
  f32x4 acc[4];
#pragma unroll
  for (int jj = 0; jj < 4; ++jj) { m_run[jj] = NEG; lsum[jj] = 0.f; }
#pragma unroll
  for (int n = 0; n < 4; ++n) acc[n] = fz;

  for (int kvt = 0; kvt <= qt; ++kvt) {
    const int kv0 = kvt * 64;
    const bool last = (kvt == qt);
    f32x4 s[4];
#pragma unroll
    for (int c = 0; c < 4; ++c) {
      if (last && c > w) {  // entire subtile above diagonal for this wave
        f32x4 neg = {NEG, NEG, NEG, NEG};
        s[c] = neg;
        continue;
      }
      const __bf16* kp = kbase + (size_t)(kv0 + c * 16) * 3072;
      bf16x8 bk0 = *(const bf16x8*)kp;
      bf16x8 bk1 = *(const bf16x8*)(kp + 32);
      f32x4 z = fz;
      z = MFMA16(aq0, bk0, z);
      z = MFMA16(aq1, bk1, z);
      const bool maskit = last && (c == w);
#pragma unroll
      for (int jj = 0; jj < 4; ++jj) {
        float v = z[jj] * 0.125f;  // 1/sqrt(64)
        if (maskit && (kv0 + c * 16 + lr > q0 + lk * 4 + jj)) v = NEG;
        s[c][jj] = v;
      }
    }
    // online softmax over this 16x64 S tile (rows owned: lk*4 + jj; cols: lanes lr x subtile c)
#pragma unroll
    for (int jj = 0; jj < 4; ++jj) {
      float mx = fmaxf(fmaxf(s[0][jj], s[1][jj]), fmaxf(s[2][jj], s[3][jj]));
      mx = fmaxf(mx, __shfl_xor(mx, 1));
      mx = fmaxf(mx, __shfl_xor(mx, 2));
      mx = fmaxf(mx, __shfl_xor(mx, 4));
      mx = fmaxf(mx, __shfl_xor(mx, 8));
      float mnew = fmaxf(m_run[jj], mx);
      float alpha = __expf(m_run[jj] - mnew);
      m_run[jj] = mnew;
      float sum = 0.f;
#pragma unroll
      for (int c = 0; c < 4; ++c) {
        float p = __expf(s[c][jj] - mnew);
        s[c][jj] = p;
        sum += p;
      }
      sum += __shfl_xor(sum, 1);
      sum += __shfl_xor(sum, 2);
      sum += __shfl_xor(sum, 4);
      sum += __shfl_xor(sum, 8);
      lsum[jj] = lsum[jj] * alpha + sum;
#pragma unroll
      for (int n = 0; n < 4; ++n) acc[n][jj] *= alpha;
    }
    // P (C-layout) -> LDS -> A-fragment layout
#pragma unroll
    for (int c = 0; c < 4; ++c) {
#pragma unroll
      for (int jj = 0; jj < 4; ++jj)
        plds[w][lk * 4 + jj][c * 16 + lr] = (__bf16)s[c][jj];
    }
    // PV: O[16x64] += P[16x64] * V[64x64]
#pragma unroll
    for (int ks = 0; ks < 2; ++ks) {
      bf16x8 ap = *(const bf16x8*)&plds[w][lr][ks * 32 + lk * 8];
#pragma unroll
      for (int n = 0; n < 4; ++n) {
        bf16x8 bv = *(const bf16x8*)(vbase + (size_t)(n * 16) * 2048 + kv0 + ks * 32);
        acc[n] = MFMA16(ap, bv, acc[n]);
      }
    }
  }

#pragma unroll
  for (int n = 0; n < 4; ++n) {
#pragma unroll
    for (int jj = 0; jj < 4; ++jj) {
      float o = acc[n][jj] / lsum[jj];
      ctx[(size_t)(b * 2048 + q0 + lk * 4 + jj) * 1024 + h * 64 + n * 16 + lr] = (__bf16)o;
    }
  }
}

extern "C" void kernel_launch(void* const* d_in, const int* in_sizes, int n_in,
                              void* d_out, int out_size, void* d_ws, size_t ws_size,
                              hipStream_t stream) {
  const float* x    = (const float*)d_in[0];   // [8192,1024]
  const float* wqkv = (const float*)d_in[1];   // [1024,3072]
  const float* wout = (const float*)d_in[2];   // [1024,1024]
  float* out = (float*)d_out;                  // [8192,1024]

  char* ws = (char*)d_ws;
  __bf16* xb    = (__bf16*)(ws);
  __bf16* wqkvT = (__bf16*)(ws + 16777216);
  __bf16* woutT = (__bf16*)(ws + 23068672);
  __bf16* qkvb  = (__bf16*)(ws + 25165824);
  __bf16* vtb   = (__bf16*)(ws + 75497472);
  __bf16* ctx   = (__bf16*)(ws + 92274688);

  k_f32_to_bf16<<<2048, 256, 0, stream>>>(x, xb, 8192 * 1024);
  k_transpose_f32_bf16<<<dim3(48, 16), 256, 0, stream>>>(wqkv, wqkvT, 1024, 3072);
  k_transpose_f32_bf16<<<dim3(16, 16), 256, 0, stream>>>(wout, woutT, 1024, 1024);
  k_gemm_bt<__bf16><<<dim3(24, 64), 256, 0, stream>>>(xb, wqkvT, qkvb, 8192, 3072, 1024);
  k_vtrans<<<dim3(32, 16, 4), 256, 0, stream>>>(qkvb, vtb);
  k_attn<<<dim3(32, 16, 4), 256, 0, stream>>>(qkvb, vtb, ctx);
  k_gemm_bt<float><<<dim3(8, 64), 256, 0, stream>>>(ctx, woutT, out, 8192, 1024, 1024);
}

// Round 2
// 247.753 us; speedup vs baseline: 2.2896x; 2.2896x over previous
//
#include <hip/hip_runtime.h>
#include <hip/hip_bf16.h>
#include <cstdint>

// CausalSelfAttention: x[4,2048,1024] @ w_qkv[1024,3072] -> causal attn (H=16, Dh=64) -> @ w_out[1024,1024]
// All heavy compute in bf16 MFMA (16x16x32), fp32 accumulate.
//
// Workspace layout (bytes):
//   xb    @ 0         : 8192*1024 bf16   (16,777,216)
//   wqkvT @ 16777216  : 3072*1024 bf16   ( 6,291,456)   w_qkv transposed to [N][K]
//   woutT @ 23068672  : 1024*1024 bf16   ( 2,097,152)   w_out  transposed to [N][K]
//   qkvb  @ 25165824  : 8192*3072 bf16   (50,331,648)
//   vtb   @ 75497472  : 4*16*64*2048 bf16(16,777,216)   V transposed to [B,H,Dh,T]
//   ctx   @ 92274688  : 8192*1024 bf16   (16,777,216)

typedef __bf16 bf16x8 __attribute__((ext_vector_type(8)));
typedef __bf16 bf16x4 __attribute__((ext_vector_type(4)));
typedef float  f32x4  __attribute__((ext_vector_type(4)));

#define MFMA16(a, b, c) __builtin_amdgcn_mfma_f32_16x16x32_bf16((a), (b), (c), 0, 0, 0)

__device__ __forceinline__ void gload16(const void* g, void* lds) {
  // global -> LDS direct copy, 16B per lane; LDS dest = wave-uniform base + lane*16
  __builtin_amdgcn_global_load_lds(
      (const __attribute__((address_space(1))) void*)(uintptr_t)g,
      (__attribute__((address_space(3))) void*)(uint32_t)(uintptr_t)lds,
      16, 0, 0);
}

// ---------------- fp32 -> bf16 elementwise ----------------
__global__ __launch_bounds__(256) void k_f32_to_bf16(const float* __restrict__ in,
                                                     __bf16* __restrict__ out, int n) {
  int idx = (blockIdx.x * 256 + threadIdx.x) * 4;
  int stride = gridDim.x * 256 * 4;
  for (; idx < n; idx += stride) {
    float4 v = *(const float4*)(in + idx);
    bf16x4 o = { (__bf16)v.x, (__bf16)v.y, (__bf16)v.z, (__bf16)v.w };
    *(bf16x4*)(out + idx) = o;
  }
}

// ---------------- fp32 [R][C] -> bf16 [C][R] transpose ----------------
__global__ __launch_bounds__(256) void k_transpose_f32_bf16(const float* __restrict__ in,
                                                            __bf16* __restrict__ out,
                                                            int R, int C) {
  __shared__ float t[64][65];
  const int r0 = blockIdx.y * 64, c0 = blockIdx.x * 64;
  const int tx = threadIdx.x & 15, ty = threadIdx.x >> 4;
#pragma unroll
  for (int rr = 0; rr < 4; ++rr) {
    int r = ty + rr * 16;
    float4 v = *(const float4*)(in + (size_t)(r0 + r) * C + c0 + tx * 4);
    t[r][tx * 4 + 0] = v.x; t[r][tx * 4 + 1] = v.y;
    t[r][tx * 4 + 2] = v.z; t[r][tx * 4 + 3] = v.w;
  }
  __syncthreads();
#pragma unroll
  for (int rr = 0; rr < 4; ++rr) {
    int c = ty + rr * 16;
    bf16x4 o = { (__bf16)t[tx * 4 + 0][c], (__bf16)t[tx * 4 + 1][c],
                 (__bf16)t[tx * 4 + 2][c], (__bf16)t[tx * 4 + 3][c] };
    *(bf16x4*)(out + (size_t)(c0 + c) * R + r0 + tx * 4) = o;
  }
}

// ---------------- V slice of qkv -> [B,H,Dh,T] ----------------
__global__ __launch_bounds__(256) void k_vtrans(const __bf16* __restrict__ qkv,
                                                __bf16* __restrict__ vt) {
  __shared__ __bf16 t[64][72];
  const int t0 = blockIdx.x * 64, h = blockIdx.y, b = blockIdx.z;
  const int tx = threadIdx.x & 15, ty = threadIdx.x >> 4;
#pragma unroll
  for (int rr = 0; rr < 4; ++rr) {
    int tt = ty + rr * 16;
    bf16x4 v = *(const bf16x4*)(qkv + (size_t)(b * 2048 + t0 + tt) * 3072 + 2048 + h * 64 + tx * 4);
    t[tt][tx * 4 + 0] = v[0]; t[tt][tx * 4 + 1] = v[1];
    t[tt][tx * 4 + 2] = v[2]; t[tt][tx * 4 + 3] = v[3];
  }
  __syncthreads();
#pragma unroll
  for (int rr = 0; rr < 4; ++rr) {
    int d = ty + rr * 16;
    bf16x4 o = { t[tx * 4 + 0][d], t[tx * 4 + 1][d], t[tx * 4 + 2][d], t[tx * 4 + 3][d] };
    *(bf16x4*)(vt + ((size_t)((b * 16 + h) * 64 + d)) * 2048 + t0 + tx * 4) = o;
  }
}

// ---------------- GEMM: C[M][N] = A[M][K] * BT[N][K]^T  (bf16 in, OutT out) ----------------
template <typename OutT>
__global__ __launch_bounds__(256) void k_gemm_bt(const __bf16* __restrict__ A,
                                                 const __bf16* __restrict__ BT,
                                                 OutT* __restrict__ C,
                                                 int M, int N, int K) {
  __shared__ __align__(16) __bf16 At[128 * 32];
  __shared__ __align__(16) __bf16 Bt[128 * 32];
  const int tid = threadIdx.x;
  const int l = tid & 63, w = tid >> 6;
  const int wr = w >> 1, wc = w & 1;
  const int lr = l & 15, lk = l >> 4;
  const int bm0 = blockIdx.y * 128, bn0 = blockIdx.x * 128;

  const int sm = w * 16 + (l >> 2);
  const int sk = (l & 3) * 8;
  const __bf16* ga0 = A + (size_t)(bm0 + sm) * K + sk;
  const __bf16* ga1 = A + (size_t)(bm0 + 64 + sm) * K + sk;
  const __bf16* gb0 = BT + (size_t)(bn0 + sm) * K + sk;
  const __bf16* gb1 = BT + (size_t)(bn0 + 64 + sm) * K + sk;
  char* lA = (char*)At + w * 1024;
  char* lB = (char*)Bt + w * 1024;

  const f32x4 fz = {0.f, 0.f, 0.f, 0.f};
  f32x4 acc[4][4];
#pragma unroll
  for (int i = 0; i < 4; ++i) {
#pragma unroll
    for (int j = 0; j < 4; ++j) acc[i][j] = fz;
  }

  for (int k0 = 0; k0 < K; k0 += 32) {
    gload16(ga0, lA);
    gload16(ga1, lA + 4096);
    gload16(gb0, lB);
    gload16(gb1, lB + 4096);
    ga0 += 32; ga1 += 32; gb0 += 32; gb1 += 32;
    __syncthreads();
    bf16x8 af[4], bfr[4];
#pragma unroll
    for (int i = 0; i < 4; ++i)
      af[i] = *(const bf16x8*)(At + (wr * 64 + i * 16 + lr) * 32 + lk * 8);
#pragma unroll
    for (int j = 0; j < 4; ++j)
      bfr[j] = *(const bf16x8*)(Bt + (wc * 64 + j * 16 + lr) * 32 + lk * 8);
#pragma unroll
    for (int i = 0; i < 4; ++i) {
#pragma unroll
      for (int j = 0; j < 4; ++j) acc[i][j] = MFMA16(af[i], bfr[j], acc[i][j]);
    }
    __syncthreads();
  }

#pragma unroll
  for (int i = 0; i < 4; ++i) {
#pragma unroll
    for (int j = 0; j < 4; ++j) {
#pragma unroll
      for (int jj = 0; jj < 4; ++jj) {
        int row = bm0 + wr * 64 + i * 16 + lk * 4 + jj;
        int col = bn0 + wc * 64 + j * 16 + lr;
        C[(size_t)row * N + col] = (OutT)acc[i][j][jj];
      }
    }
  }
}

// ---------------- causal flash attention, v2 ----------------
// Balanced pairing: block p handles q-tiles {31-p, p} -> every block does 33 KV iterations.
// K/V tiles staged in double-buffered, XOR-swizzled LDS shared by 4 waves; prefetch t+1
// while computing t. Grid (16,16,4) = 1024 blocks = exactly 4 blocks/CU (40 KB LDS each).
__global__ __launch_bounds__(256, 4) void k_attn(const __bf16* __restrict__ qkv,
                                                 const __bf16* __restrict__ vt,
                                                 __bf16* __restrict__ ctx) {
  const int p = blockIdx.x, h = blockIdx.y, b = blockIdx.z;
  const int l = threadIdx.x & 63, w = threadIdx.x >> 6;
  const int lr = l & 15, lk = l >> 4;
  const int lr7 = lr & 7;

  __shared__ __align__(16) __bf16 Kt[2][64 * 64];  // 16 KB
  __shared__ __align__(16) __bf16 Vt[2][64 * 64];  // 16 KB
  __shared__ __align__(16) __bf16 Pt[4][16 * 64];  //  8 KB (per-wave P, swizzled)

  // swizzle: LDS 16B-block jb of row r holds global 16B-block (jb ^ (r&7)).
  // staging: wave w instr i lane l -> LDS byte i*4096 + w*1024 + l*16
  //          => row r = i*32 + w*8 + (l>>3), block jb = l&7
  //          => global col block = (l&7) ^ (l>>3)
  const int srow = w * 8 + (l >> 3);
  const int scol = ((l & 7) ^ (l >> 3)) * 8;  // element offset in 64-elem row

  const __bf16* gK = qkv + (size_t)(b * 2048) * 3072 + 1024 + h * 64;  // K rows, stride 3072
  const __bf16* gV = vt + (size_t)((b * 16 + h) * 64) * 2048;          // dh rows, stride 2048

  const float NEG = -1e30f;
  const f32x4 fz = {0.f, 0.f, 0.f, 0.f};

  const int qts[2] = {31 - p, p};
#pragma unroll 1
  for (int ti = 0; ti < 2; ++ti) {
    const int qt = qts[ti];
    const int q0 = qt * 64 + w * 16;

    const __bf16* qp = qkv + (size_t)(b * 2048 + q0 + lr) * 3072 + h * 64 + lk * 8;
    bf16x8 aq0 = *(const bf16x8*)qp;
    bf16x8 aq1 = *(const bf16x8*)(qp + 32);

    float m_run[4], lsum[4];
    f32x4 acc[4];
#pragma unroll
    for (int jj = 0; jj < 4; ++jj) { m_run[jj] = NEG; lsum[jj] = 0.f; }
#pragma unroll
    for (int n = 0; n < 4; ++n) acc[n] = fz;

    // prologue: stage tile 0 into buf 0
#pragma unroll
    for (int i = 0; i < 2; ++i) {
      gload16(gK + (size_t)(i * 32 + srow) * 3072 + scol, (char*)Kt[0] + i * 4096 + w * 1024);
      gload16(gV + (size_t)(i * 32 + srow) * 2048 + scol, (char*)Vt[0] + i * 4096 + w * 1024);
    }
    __syncthreads();  // compiler drains vmcnt before s_barrier

#pragma unroll 1
    for (int kvt = 0; kvt <= qt; ++kvt) {
      const int cur = kvt & 1;
      const int kv0 = kvt * 64;
      if (kvt < qt) {  // prefetch next tile into other buffer
        const int nk0 = kv0 + 64;
#pragma unroll
        for (int i = 0; i < 2; ++i) {
          gload16(gK + (size_t)(nk0 + i * 32 + srow) * 3072 + scol,
                  (char*)Kt[cur ^ 1] + i * 4096 + w * 1024);
          gload16(gV + (size_t)(i * 32 + srow) * 2048 + nk0 + scol,
                  (char*)Vt[cur ^ 1] + i * 4096 + w * 1024);
        }
      }
      const __bf16* Kb = Kt[cur];
      const __bf16* Vb = Vt[cur];
      const bool last = (kvt == qt);

      // ---- S = Q K^T (per-wave 16x64), swizzled LDS reads ----
      f32x4 s[4];
#pragma unroll
      for (int c = 0; c < 4; ++c) {
        if (last && c > w) { f32x4 neg = {NEG, NEG, NEG, NEG}; s[c] = neg; continue; }
        const __bf16* kr = Kb + (c * 16 + lr) * 64;
        bf16x8 bk0 = *(const bf16x8*)(kr + ((lk ^ lr7) * 8));
        bf16x8 bk1 = *(const bf16x8*)(kr + (((4 + lk) ^ lr7) * 8));
        f32x4 z = fz;
        z = MFMA16(aq0, bk0, z);
        z = MFMA16(aq1, bk1, z);
        const bool maskit = last && (c == w);
#pragma unroll
        for (int jj = 0; jj < 4; ++jj) {
          float v = z[jj] * 0.125f;  // 1/sqrt(64)
          if (maskit && (kv0 + c * 16 + lr > q0 + lk * 4 + jj)) v = NEG;
          s[c][jj] = v;
        }
      }

      // ---- online softmax (rows: lk*4+jj, cols: lr x subtile c) ----
#pragma unroll
      for (int jj = 0; jj < 4; ++jj) {
        float mx = fmaxf(fmaxf(s[0][jj], s[1][jj]), fmaxf(s[2][jj], s[3][jj]));
        mx = fmaxf(mx, __shfl_xor(mx, 1));
        mx = fmaxf(mx, __shfl_xor(mx, 2));
        mx = fmaxf(mx, __shfl_xor(mx, 4));
        mx = fmaxf(mx, __shfl_xor(mx, 8));
        float mnew = fmaxf(m_run[jj], mx);
        float alpha = __expf(m_run[jj] - mnew);
        m_run[jj] = mnew;
        float sum = 0.f;
#pragma unroll
        for (int c = 0; c < 4; ++c) {
          float pv = __expf(s[c][jj] - mnew);
          s[c][jj] = pv;
          sum += pv;
        }
        sum += __shfl_xor(sum, 1);
        sum += __shfl_xor(sum, 2);
        sum += __shfl_xor(sum, 4);
        sum += __shfl_xor(sum, 8);
        lsum[jj] = lsum[jj] * alpha + sum;
#pragma unroll
        for (int n = 0; n < 4; ++n) acc[n][jj] *= alpha;
      }

      // ---- P (C-layout) -> swizzled per-wave LDS ----
#pragma unroll
      for (int c = 0; c < 4; ++c) {
#pragma unroll
        for (int jj = 0; jj < 4; ++jj) {
          const int row = lk * 4 + jj;
          Pt[w][row * 64 + (((c * 2 + (lr >> 3)) ^ (row & 7)) * 8) + lr7] = (__bf16)s[c][jj];
        }
      }

      // ---- PV: O[16x64] += P[16x64] * V[64x64] ----
#pragma unroll
      for (int ks = 0; ks < 2; ++ks) {
        bf16x8 ap = *(const bf16x8*)(Pt[w] + lr * 64 + (((ks * 4 + lk) ^ lr7) * 8));
#pragma unroll
        for (int n = 0; n < 4; ++n) {
          bf16x8 bv = *(const bf16x8*)(Vb + (n * 16 + lr) * 64 + (((ks * 4 + lk) ^ lr7) * 8));
          acc[n] = MFMA16(ap, bv, acc[n]);
        }
      }
      __syncthreads();  // drain (vmcnt incl. prefetch) + sync before buffer swap
    }

    // ---- write context tile ----
#pragma unroll
    for (int n = 0; n < 4; ++n) {
#pragma unroll
      for (int jj = 0; jj < 4; ++jj) {
        float o = acc[n][jj] / lsum[jj];
        ctx[(size_t)(b * 2048 + q0 + lk * 4 + jj) * 1024 + h * 64 + n * 16 + lr] = (__bf16)o;
      }
    }
    __syncthreads();  // protect LDS before next q-tile's prologue overwrites
  }
}

extern "C" void kernel_launch(void* const* d_in, const int* in_sizes, int n_in,
                              void* d_out, int out_size, void* d_ws, size_t ws_size,
                              hipStream_t stream) {
  const float* x    = (const float*)d_in[0];   // [8192,1024]
  const float* wqkv = (const float*)d_in[1];   // [1024,3072]
  const float* wout = (const float*)d_in[2];   // [1024,1024]
  float* out = (float*)d_out;                  // [8192,1024]

  char* ws = (char*)d_ws;
  __bf16* xb    = (__bf16*)(ws);
  __bf16* wqkvT = (__bf16*)(ws + 16777216);
  __bf16* woutT = (__bf16*)(ws + 23068672);
  __bf16* qkvb  = (__bf16*)(ws + 25165824);
  __bf16* vtb   = (__bf16*)(ws + 75497472);
  __bf16* ctx   = (__bf16*)(ws + 92274688);

  k_f32_to_bf16<<<2048, 256, 0, stream>>>(x, xb, 8192 * 1024);
  k_transpose_f32_bf16<<<dim3(48, 16), 256, 0, stream>>>(wqkv, wqkvT, 1024, 3072);
  k_transpose_f32_bf16<<<dim3(16, 16), 256, 0, stream>>>(wout, woutT, 1024, 1024);
  k_gemm_bt<__bf16><<<dim3(24, 64), 256, 0, stream>>>(xb, wqkvT, qkvb, 8192, 3072, 1024);
  k_vtrans<<<dim3(32, 16, 4), 256, 0, stream>>>(qkvb, vtb);
  k_attn<<<dim3(16, 16, 4), 256, 0, stream>>>(qkvb, vtb, ctx);
  k_gemm_bt<float><<<dim3(8, 64), 256, 0, stream>>>(ctx, woutT, out, 8192, 1024, 1024);
}

// Round 3
// 195.341 us; speedup vs baseline: 2.9039x; 1.2683x over previous
//
#include <hip/hip_runtime.h>
#include <hip/hip_bf16.h>
#include <cstdint>

// CausalSelfAttention: x[4,2048,1024] @ w_qkv[1024,3072] -> causal attn (H=16, Dh=64) -> @ w_out[1024,1024]
// All heavy compute in bf16 MFMA, fp32 accumulate.
//
// Workspace layout (bytes):
//   xb    @ 0         : 8192*1024 bf16   (16,777,216)
//   wqkvT @ 16777216  : 3072*1024 bf16   ( 6,291,456)   w_qkv transposed to [N][K]; Q rows pre-scaled by 0.125
//   woutT @ 23068672  : 1024*1024 bf16   ( 2,097,152)   w_out  transposed to [N][K]
//   qkvb  @ 25165824  : 8192*3072 bf16   (50,331,648)
//   vtb   @ 75497472  : 4*16*64*2048 bf16(16,777,216)   V transposed to [B,H,Dh,T]
//   ctx   @ 92274688  : 8192*1024 bf16   (16,777,216)

typedef __bf16 bf16x8 __attribute__((ext_vector_type(8)));
typedef __bf16 bf16x4 __attribute__((ext_vector_type(4)));
typedef float  f32x4  __attribute__((ext_vector_type(4)));
typedef float  f32x16 __attribute__((ext_vector_type(16)));
typedef unsigned int u32x4 __attribute__((ext_vector_type(4)));
typedef unsigned int u32x2 __attribute__((ext_vector_type(2)));

#define MFMA16(a, b, c) __builtin_amdgcn_mfma_f32_16x16x32_bf16((a), (b), (c), 0, 0, 0)
#define MFMA32(a, b, c) __builtin_amdgcn_mfma_f32_32x32x16_bf16((a), (b), (c), 0, 0, 0)

__device__ __forceinline__ void gload16(const void* g, void* lds) {
  __builtin_amdgcn_global_load_lds(
      (const __attribute__((address_space(1))) void*)(uintptr_t)g,
      (__attribute__((address_space(3))) void*)(uint32_t)(uintptr_t)lds,
      16, 0, 0);
}

__device__ __forceinline__ uint32_t packbf(float a, float b) {
  uint16_t lo = __builtin_bit_cast(uint16_t, (__bf16)a);
  uint16_t hi = __builtin_bit_cast(uint16_t, (__bf16)b);
  return (uint32_t)lo | ((uint32_t)hi << 16);
}

// ---------------- fp32 -> bf16 elementwise ----------------
__global__ __launch_bounds__(256) void k_f32_to_bf16(const float* __restrict__ in,
                                                     __bf16* __restrict__ out, int n) {
  int idx = (blockIdx.x * 256 + threadIdx.x) * 4;
  int stride = gridDim.x * 256 * 4;
  for (; idx < n; idx += stride) {
    float4 v = *(const float4*)(in + idx);
    bf16x4 o = { (__bf16)v.x, (__bf16)v.y, (__bf16)v.z, (__bf16)v.w };
    *(bf16x4*)(out + idx) = o;
  }
}

// ---------------- fp32 [R][C] -> bf16 [C][R] transpose; out-rows < nscale get *scale ----------------
__global__ __launch_bounds__(256) void k_transpose_f32_bf16(const float* __restrict__ in,
                                                            __bf16* __restrict__ out,
                                                            int R, int C, float scale, int nscale) {
  __shared__ float t[64][65];
  const int r0 = blockIdx.y * 64, c0 = blockIdx.x * 64;
  const int tx = threadIdx.x & 15, ty = threadIdx.x >> 4;
#pragma unroll
  for (int rr = 0; rr < 4; ++rr) {
    int r = ty + rr * 16;
    float4 v = *(const float4*)(in + (size_t)(r0 + r) * C + c0 + tx * 4);
    t[r][tx * 4 + 0] = v.x; t[r][tx * 4 + 1] = v.y;
    t[r][tx * 4 + 2] = v.z; t[r][tx * 4 + 3] = v.w;
  }
  __syncthreads();
#pragma unroll
  for (int rr = 0; rr < 4; ++rr) {
    int c = ty + rr * 16;
    float sc = (c0 + c < nscale) ? scale : 1.0f;
    bf16x4 o = { (__bf16)(t[tx * 4 + 0][c] * sc), (__bf16)(t[tx * 4 + 1][c] * sc),
                 (__bf16)(t[tx * 4 + 2][c] * sc), (__bf16)(t[tx * 4 + 3][c] * sc) };
    *(bf16x4*)(out + (size_t)(c0 + c) * R + r0 + tx * 4) = o;
  }
}

// ---------------- V slice of qkv -> [B,H,Dh,T] ----------------
__global__ __launch_bounds__(256) void k_vtrans(const __bf16* __restrict__ qkv,
                                                __bf16* __restrict__ vt) {
  __shared__ __bf16 t[64][72];
  const int t0 = blockIdx.x * 64, h = blockIdx.y, b = blockIdx.z;
  const int tx = threadIdx.x & 15, ty = threadIdx.x >> 4;
#pragma unroll
  for (int rr = 0; rr < 4; ++rr) {
    int tt = ty + rr * 16;
    bf16x4 v = *(const bf16x4*)(qkv + (size_t)(b * 2048 + t0 + tt) * 3072 + 2048 + h * 64 + tx * 4);
    t[tt][tx * 4 + 0] = v[0]; t[tt][tx * 4 + 1] = v[1];
    t[tt][tx * 4 + 2] = v[2]; t[tt][tx * 4 + 3] = v[3];
  }
  __syncthreads();
#pragma unroll
  for (int rr = 0; rr < 4; ++rr) {
    int d = ty + rr * 16;
    bf16x4 o = { t[tx * 4 + 0][d], t[tx * 4 + 1][d], t[tx * 4 + 2][d], t[tx * 4 + 3][d] };
    *(bf16x4*)(vt + ((size_t)((b * 16 + h) * 64 + d)) * 2048 + t0 + tx * 4) = o;
  }
}

// ---------------- GEMM: C[M][N] = A[M][K] * BT[N][K]^T  (bf16 in, OutT out) ----------------
template <typename OutT>
__global__ __launch_bounds__(256) void k_gemm_bt(const __bf16* __restrict__ A,
                                                 const __bf16* __restrict__ BT,
                                                 OutT* __restrict__ C,
                                                 int M, int N, int K) {
  __shared__ __align__(16) __bf16 At[128 * 32];
  __shared__ __align__(16) __bf16 Bt[128 * 32];
  const int tid = threadIdx.x;
  const int l = tid & 63, w = tid >> 6;
  const int wr = w >> 1, wc = w & 1;
  const int lr = l & 15, lk = l >> 4;
  const int bm0 = blockIdx.y * 128, bn0 = blockIdx.x * 128;

  const int sm = w * 16 + (l >> 2);
  const int sk = (l & 3) * 8;
  const __bf16* ga0 = A + (size_t)(bm0 + sm) * K + sk;
  const __bf16* ga1 = A + (size_t)(bm0 + 64 + sm) * K + sk;
  const __bf16* gb0 = BT + (size_t)(bn0 + sm) * K + sk;
  const __bf16* gb1 = BT + (size_t)(bn0 + 64 + sm) * K + sk;
  char* lA = (char*)At + w * 1024;
  char* lB = (char*)Bt + w * 1024;

  const f32x4 fz = {0.f, 0.f, 0.f, 0.f};
  f32x4 acc[4][4];
#pragma unroll
  for (int i = 0; i < 4; ++i) {
#pragma unroll
    for (int j = 0; j < 4; ++j) acc[i][j] = fz;
  }

  for (int k0 = 0; k0 < K; k0 += 32) {
    gload16(ga0, lA);
    gload16(ga1, lA + 4096);
    gload16(gb0, lB);
    gload16(gb1, lB + 4096);
    ga0 += 32; ga1 += 32; gb0 += 32; gb1 += 32;
    __syncthreads();
    bf16x8 af[4], bfr[4];
#pragma unroll
    for (int i = 0; i < 4; ++i)
      af[i] = *(const bf16x8*)(At + (wr * 64 + i * 16 + lr) * 32 + lk * 8);
#pragma unroll
    for (int j = 0; j < 4; ++j)
      bfr[j] = *(const bf16x8*)(Bt + (wc * 64 + j * 16 + lr) * 32 + lk * 8);
#pragma unroll
    for (int i = 0; i < 4; ++i) {
#pragma unroll
      for (int j = 0; j < 4; ++j) acc[i][j] = MFMA16(af[i], bfr[j], acc[i][j]);
    }
    __syncthreads();
  }

#pragma unroll
  for (int i = 0; i < 4; ++i) {
#pragma unroll
    for (int j = 0; j < 4; ++j) {
#pragma unroll
      for (int jj = 0; jj < 4; ++jj) {
        int row = bm0 + wr * 64 + i * 16 + lk * 4 + jj;
        int col = bn0 + wc * 64 + j * 16 + lr;
        C[(size_t)row * N + col] = (OutT)acc[i][j][jj];
      }
    }
  }
}

// ---------------- causal flash attention, v3: swapped QK^T, in-register softmax ----------------
// 4 waves x QBLK=32 = 128 q-rows/block; KVBLK=64 double-buffered in swizzled LDS.
// Balanced pairing: block p handles q-blocks {15-p, p} (34 KV iterations each).
// S^T = mfma32(K_frag, Q_frag): lane owns one q-row, 32 S values in regs.
// P -> bf16 words via pack + permlane32_swap (T12); PV: O^T = mfma32(V^T, P^T).
__global__ __launch_bounds__(256, 2) void k_attn(const __bf16* __restrict__ qkv,
                                                 const __bf16* __restrict__ vt,
                                                 __bf16* __restrict__ ctx) {
  const int p = blockIdx.x, h = blockIdx.y, b = blockIdx.z;
  const int l = threadIdx.x & 63, w = threadIdx.x >> 6;
  const int q = l & 31, hi = l >> 5, l7 = l & 7;

  // [buf][0]=K tile [64k][64d], [buf][1]=V^T tile [64d][64k]; 16B-block XOR swizzle
  __shared__ __align__(16) __bf16 KVs[2][2][64 * 64];  // 32 KB

  const int srow = w * 8 + (l >> 3);
  const int scol = ((l & 7) ^ (l >> 3)) * 8;

  const __bf16* gK = qkv + (size_t)(b * 2048) * 3072 + 1024 + h * 64;  // stride 3072
  const __bf16* gV = vt + (size_t)((b * 16 + h) * 64) * 2048;          // stride 2048

  const float NEG = -1e30f;

#pragma unroll 1
  for (int ti = 0; ti < 2; ++ti) {
    const int qb = (ti == 0) ? (15 - p) : p;
    const int q0w = qb * 128 + w * 32;
    const int qg = q0w + q;
    const int nkv = 2 * qb + 2;
    const int kvlast = (q0w + 31) >> 6;

    // Q B-fragments (w_qkv Q-columns pre-scaled by 0.125)
    const __bf16* qp = qkv + (size_t)(b * 2048 + qg) * 3072 + h * 64 + hi * 8;
    bf16x8 qf[4];
#pragma unroll
    for (int d0 = 0; d0 < 4; ++d0) qf[d0] = *(const bf16x8*)(qp + d0 * 16);

    float m_run = NEG, lsum = 0.f;
    f32x16 o0 = (f32x16)(0.0f), o1 = (f32x16)(0.0f);

    // prologue: stage tile 0 into buf 0
#pragma unroll
    for (int i = 0; i < 2; ++i) {
      gload16(gK + (size_t)(i * 32 + srow) * 3072 + scol, (char*)&KVs[0][0][0] + i * 4096 + w * 1024);
      gload16(gV + (size_t)(i * 32 + srow) * 2048 + scol, (char*)&KVs[0][1][0] + i * 4096 + w * 1024);
    }
    __syncthreads();

#pragma unroll 1
    for (int kvt = 0; kvt < nkv; ++kvt) {
      const int cur = kvt & 1;
      const int kv0 = kvt * 64;
      if (kvt + 1 < nkv) {  // prefetch next tile
        const int nk0 = kv0 + 64;
#pragma unroll
        for (int i = 0; i < 2; ++i) {
          gload16(gK + (size_t)(nk0 + i * 32 + srow) * 3072 + scol,
                  (char*)&KVs[cur ^ 1][0][0] + i * 4096 + w * 1024);
          gload16(gV + (size_t)(i * 32 + srow) * 2048 + nk0 + scol,
                  (char*)&KVs[cur ^ 1][1][0] + i * 4096 + w * 1024);
        }
      }
      if (kvt <= kvlast) {
        const __bf16* Kb = &KVs[cur][0][0];
        const __bf16* Vb = &KVs[cur][1][0];

        // ---- S^T[64k x 32q] = K * Q^T ----
        f32x16 s0 = (f32x16)(0.0f), s1 = (f32x16)(0.0f);
#pragma unroll
        for (int d0 = 0; d0 < 4; ++d0) {
          bf16x8 k0 = *(const bf16x8*)(Kb + (size_t)q * 64 + (((d0 * 2 + hi) ^ l7) * 8));
          bf16x8 k1 = *(const bf16x8*)(Kb + (size_t)(32 + q) * 64 + (((d0 * 2 + hi) ^ l7) * 8));
          s0 = MFMA32(k0, qf[d0], s0);
          s1 = MFMA32(k1, qf[d0], s1);
        }

        // ---- causal mask (diagonal tile only) ----
        if (kvt == kvlast) {
#pragma unroll
          for (int r = 0; r < 16; ++r) {
            const int kl = (r & 3) + 8 * (r >> 2) + 4 * hi;
            if (kv0 + kl > qg) s0[r] = NEG;
            if (kv0 + 32 + kl > qg) s1[r] = NEG;
          }
        }

        // ---- row max (in-lane tree + one cross-half shuffle) ----
        float t[8];
#pragma unroll
        for (int i = 0; i < 8; ++i)
          t[i] = fmaxf(fmaxf(s0[i], s0[i + 8]), fmaxf(s1[i], s1[i + 8]));
#pragma unroll
        for (int i = 0; i < 4; ++i) t[i] = fmaxf(t[i], t[i + 4]);
        float mt = fmaxf(fmaxf(t[0], t[1]), fmaxf(t[2], t[3]));
        mt = fmaxf(mt, __shfl_xor(mt, 32));

        // ---- defer-max rescale (T13, THR=8) ----
        if (!__all(mt - m_run <= 8.0f)) {
          const float al = __expf(m_run - mt);
          lsum *= al;
#pragma unroll
          for (int r = 0; r < 16; ++r) { o0[r] *= al; o1[r] *= al; }
          m_run = mt;
        }

        // ---- p = exp(s - m), row sum ----
#pragma unroll
        for (int r = 0; r < 16; ++r) {
          s0[r] = __expf(s0[r] - m_run);
          s1[r] = __expf(s1[r] - m_run);
        }
        float sa[8];
#pragma unroll
        for (int i = 0; i < 8; ++i) sa[i] = (s0[i] + s0[i + 8]) + (s1[i] + s1[i + 8]);
#pragma unroll
        for (int i = 0; i < 4; ++i) sa[i] += sa[i + 4];
        float sm = (sa[0] + sa[1]) + (sa[2] + sa[3]);
        sm += __shfl_xor(sm, 32);
        lsum += sm;

        // ---- pack P -> bf16 B-fragments via permlane32_swap (T12) ----
        uint32_t c0[8], c1[8];
#pragma unroll
        for (int j = 0; j < 8; ++j) {
          c0[j] = packbf(s0[2 * j], s0[2 * j + 1]);
          c1[j] = packbf(s1[2 * j], s1[2 * j + 1]);
        }
        u32x4 pk[4];
        {
          u32x2 r0 = __builtin_amdgcn_permlane32_swap(c0[0], c0[2], false, false);
          u32x2 r1 = __builtin_amdgcn_permlane32_swap(c0[1], c0[3], false, false);
          u32x2 r2 = __builtin_amdgcn_permlane32_swap(c0[4], c0[6], false, false);
          u32x2 r3 = __builtin_amdgcn_permlane32_swap(c0[5], c0[7], false, false);
          pk[0].x = r0.x; pk[0].y = r1.x; pk[0].z = r0.y; pk[0].w = r1.y;
          pk[1].x = r2.x; pk[1].y = r3.x; pk[1].z = r2.y; pk[1].w = r3.y;
          u32x2 r4 = __builtin_amdgcn_permlane32_swap(c1[0], c1[2], false, false);
          u32x2 r5 = __builtin_amdgcn_permlane32_swap(c1[1], c1[3], false, false);
          u32x2 r6 = __builtin_amdgcn_permlane32_swap(c1[4], c1[6], false, false);
          u32x2 r7 = __builtin_amdgcn_permlane32_swap(c1[5], c1[7], false, false);
          pk[2].x = r4.x; pk[2].y = r5.x; pk[2].z = r4.y; pk[2].w = r5.y;
          pk[3].x = r6.x; pk[3].y = r7.x; pk[3].z = r6.y; pk[3].w = r7.y;
        }
        bf16x8 pf[4];
#pragma unroll
        for (int kc = 0; kc < 4; ++kc) pf[kc] = __builtin_bit_cast(bf16x8, pk[kc]);

        // ---- PV: O^T[64d x 32q] += V^T * P^T ----
#pragma unroll
        for (int kc = 0; kc < 4; ++kc) {
          bf16x8 vf0 = *(const bf16x8*)(Vb + (size_t)q * 64 + (((kc * 2 + hi) ^ l7) * 8));
          o0 = MFMA32(vf0, pf[kc], o0);
        }
#pragma unroll
        for (int kc = 0; kc < 4; ++kc) {
          bf16x8 vf1 = *(const bf16x8*)(Vb + (size_t)(32 + q) * 64 + (((kc * 2 + hi) ^ l7) * 8));
          o1 = MFMA32(vf1, pf[kc], o1);
        }
      }
      __syncthreads();  // drain staging + protect buffer swap
    }

    // ---- epilogue: O^T regs -> LDS (stride 72) -> coalesced global ----
    const float inv = 1.0f / lsum;
    __bf16* Ol = &KVs[0][0][0];
#pragma unroll
    for (int r = 0; r < 16; ++r) {
      const int d = (r & 3) + 8 * (r >> 2) + 4 * hi;
      Ol[(w * 32 + q) * 72 + d]      = (__bf16)(o0[r] * inv);
      Ol[(w * 32 + q) * 72 + 32 + d] = (__bf16)(o1[r] * inv);
    }
    __syncthreads();
    {
      const int row = threadIdx.x >> 1, half = threadIdx.x & 1;
      const __bf16* src = Ol + row * 72 + half * 32;
      __bf16* dst = ctx + (size_t)(b * 2048 + qb * 128 + row) * 1024 + h * 64 + half * 32;
#pragma unroll
      for (int i = 0; i < 4; ++i)
        *(bf16x8*)(dst + i * 8) = *(const bf16x8*)(src + i * 8);
    }
    __syncthreads();  // LDS free before next q-block prologue
  }
}

extern "C" void kernel_launch(void* const* d_in, const int* in_sizes, int n_in,
                              void* d_out, int out_size, void* d_ws, size_t ws_size,
                              hipStream_t stream) {
  const float* x    = (const float*)d_in[0];   // [8192,1024]
  const float* wqkv = (const float*)d_in[1];   // [1024,3072]
  const float* wout = (const float*)d_in[2];   // [1024,1024]
  float* out = (float*)d_out;                  // [8192,1024]

  char* ws = (char*)d_ws;
  __bf16* xb    = (__bf16*)(ws);
  __bf16* wqkvT = (__bf16*)(ws + 16777216);
  __bf16* woutT = (__bf16*)(ws + 23068672);
  __bf16* qkvb  = (__bf16*)(ws + 25165824);
  __bf16* vtb   = (__bf16*)(ws + 75497472);
  __bf16* ctx   = (__bf16*)(ws + 92274688);

  k_f32_to_bf16<<<2048, 256, 0, stream>>>(x, xb, 8192 * 1024);
  k_transpose_f32_bf16<<<dim3(48, 16), 256, 0, stream>>>(wqkv, wqkvT, 1024, 3072, 0.125f, 1024);
  k_transpose_f32_bf16<<<dim3(16, 16), 256, 0, stream>>>(wout, woutT, 1024, 1024, 1.0f, 0);
  k_gemm_bt<__bf16><<<dim3(24, 64), 256, 0, stream>>>(xb, wqkvT, qkvb, 8192, 3072, 1024);
  k_vtrans<<<dim3(32, 16, 4), 256, 0, stream>>>(qkvb, vtb);
  k_attn<<<dim3(8, 16, 4), 256, 0, stream>>>(qkvb, vtb, ctx);
  k_gemm_bt<float><<<dim3(8, 64), 256, 0, stream>>>(ctx, woutT, out, 8192, 1024, 1024);
}

// Round 4
// 185.289 us; speedup vs baseline: 3.0614x; 1.0542x over previous
//
#include <hip/hip_runtime.h>
#include <hip/hip_bf16.h>
#include <cstdint>

// CausalSelfAttention: x[4,2048,1024] @ w_qkv[1024,3072] -> causal attn (H=16, Dh=64) -> @ w_out[1024,1024]
// All heavy compute in bf16 MFMA, fp32 accumulate.
//
// Workspace layout (bytes):
//   xb    @ 0         : 8192*1024 bf16   (16,777,216)
//   wqkvT @ 16777216  : 3072*1024 bf16   ( 6,291,456)   w_qkv transposed to [N][K]; Q rows pre-scaled by 0.125
//   woutT @ 23068672  : 1024*1024 bf16   ( 2,097,152)   w_out  transposed to [N][K]
//   qkvb  @ 25165824  : 8192*3072 bf16   (50,331,648)
//   vtb   @ 75497472  : 4*16*64*2048 bf16(16,777,216)   V transposed to [B,H,Dh,T]
//   ctx   @ 92274688  : 8192*1024 bf16   (16,777,216)

typedef __bf16 bf16x8 __attribute__((ext_vector_type(8)));
typedef __bf16 bf16x4 __attribute__((ext_vector_type(4)));
typedef float  f32x4  __attribute__((ext_vector_type(4)));
typedef float  f32x16 __attribute__((ext_vector_type(16)));
typedef unsigned int u32x4 __attribute__((ext_vector_type(4)));
typedef unsigned int u32x2 __attribute__((ext_vector_type(2)));

#define MFMA16(a, b, c) __builtin_amdgcn_mfma_f32_16x16x32_bf16((a), (b), (c), 0, 0, 0)
#define MFMA32(a, b, c) __builtin_amdgcn_mfma_f32_32x32x16_bf16((a), (b), (c), 0, 0, 0)

__device__ __forceinline__ void gload16(const void* g, void* lds) {
  __builtin_amdgcn_global_load_lds(
      (const __attribute__((address_space(1))) void*)(uintptr_t)g,
      (__attribute__((address_space(3))) void*)(uint32_t)(uintptr_t)lds,
      16, 0, 0);
}

__device__ __forceinline__ uint32_t packbf(float a, float b) {
  uint16_t lo = __builtin_bit_cast(uint16_t, (__bf16)a);
  uint16_t hi = __builtin_bit_cast(uint16_t, (__bf16)b);
  return (uint32_t)lo | ((uint32_t)hi << 16);
}

// ---------------- fp32 -> bf16 elementwise ----------------
__global__ __launch_bounds__(256) void k_f32_to_bf16(const float* __restrict__ in,
                                                     __bf16* __restrict__ out, int n) {
  int idx = (blockIdx.x * 256 + threadIdx.x) * 4;
  int stride = gridDim.x * 256 * 4;
  for (; idx < n; idx += stride) {
    float4 v = *(const float4*)(in + idx);
    bf16x4 o = { (__bf16)v.x, (__bf16)v.y, (__bf16)v.z, (__bf16)v.w };
    *(bf16x4*)(out + idx) = o;
  }
}

// ---------------- fp32 [R][C] -> bf16 [C][R] transpose; out-rows < nscale get *scale ----------------
__global__ __launch_bounds__(256) void k_transpose_f32_bf16(const float* __restrict__ in,
                                                            __bf16* __restrict__ out,
                                                            int R, int C, float scale, int nscale) {
  __shared__ float t[64][65];
  const int r0 = blockIdx.y * 64, c0 = blockIdx.x * 64;
  const int tx = threadIdx.x & 15, ty = threadIdx.x >> 4;
#pragma unroll
  for (int rr = 0; rr < 4; ++rr) {
    int r = ty + rr * 16;
    float4 v = *(const float4*)(in + (size_t)(r0 + r) * C + c0 + tx * 4);
    t[r][tx * 4 + 0] = v.x; t[r][tx * 4 + 1] = v.y;
    t[r][tx * 4 + 2] = v.z; t[r][tx * 4 + 3] = v.w;
  }
  __syncthreads();
#pragma unroll
  for (int rr = 0; rr < 4; ++rr) {
    int c = ty + rr * 16;
    float sc = (c0 + c < nscale) ? scale : 1.0f;
    bf16x4 o = { (__bf16)(t[tx * 4 + 0][c] * sc), (__bf16)(t[tx * 4 + 1][c] * sc),
                 (__bf16)(t[tx * 4 + 2][c] * sc), (__bf16)(t[tx * 4 + 3][c] * sc) };
    *(bf16x4*)(out + (size_t)(c0 + c) * R + r0 + tx * 4) = o;
  }
}

// ---------------- V slice of qkv -> [B,H,Dh,T] ----------------
__global__ __launch_bounds__(256) void k_vtrans(const __bf16* __restrict__ qkv,
                                                __bf16* __restrict__ vt) {
  __shared__ __bf16 t[64][72];
  const int t0 = blockIdx.x * 64, h = blockIdx.y, b = blockIdx.z;
  const int tx = threadIdx.x & 15, ty = threadIdx.x >> 4;
#pragma unroll
  for (int rr = 0; rr < 4; ++rr) {
    int tt = ty + rr * 16;
    bf16x4 v = *(const bf16x4*)(qkv + (size_t)(b * 2048 + t0 + tt) * 3072 + 2048 + h * 64 + tx * 4);
    t[tt][tx * 4 + 0] = v[0]; t[tt][tx * 4 + 1] = v[1];
    t[tt][tx * 4 + 2] = v[2]; t[tt][tx * 4 + 3] = v[3];
  }
  __syncthreads();
#pragma unroll
  for (int rr = 0; rr < 4; ++rr) {
    int d = ty + rr * 16;
    bf16x4 o = { t[tx * 4 + 0][d], t[tx * 4 + 1][d], t[tx * 4 + 2][d], t[tx * 4 + 3][d] };
    *(bf16x4*)(vt + ((size_t)((b * 16 + h) * 64 + d)) * 2048 + t0 + tx * 4) = o;
  }
}

// ---------------- GEMM 128x128 (m97 structure), used for the out-projection ----------------
template <typename OutT>
__global__ __launch_bounds__(256) void k_gemm_bt(const __bf16* __restrict__ A,
                                                 const __bf16* __restrict__ BT,
                                                 OutT* __restrict__ C,
                                                 int M, int N, int K) {
  __shared__ __align__(16) __bf16 At[128 * 32];
  __shared__ __align__(16) __bf16 Bt[128 * 32];
  const int tid = threadIdx.x;
  const int l = tid & 63, w = tid >> 6;
  const int wr = w >> 1, wc = w & 1;
  const int lr = l & 15, lk = l >> 4;
  const int bm0 = blockIdx.y * 128, bn0 = blockIdx.x * 128;

  const int sm = w * 16 + (l >> 2);
  const int sk = (l & 3) * 8;
  const __bf16* ga0 = A + (size_t)(bm0 + sm) * K + sk;
  const __bf16* ga1 = A + (size_t)(bm0 + 64 + sm) * K + sk;
  const __bf16* gb0 = BT + (size_t)(bn0 + sm) * K + sk;
  const __bf16* gb1 = BT + (size_t)(bn0 + 64 + sm) * K + sk;
  char* lA = (char*)At + w * 1024;
  char* lB = (char*)Bt + w * 1024;

  const f32x4 fz = {0.f, 0.f, 0.f, 0.f};
  f32x4 acc[4][4];
#pragma unroll
  for (int i = 0; i < 4; ++i) {
#pragma unroll
    for (int j = 0; j < 4; ++j) acc[i][j] = fz;
  }

  for (int k0 = 0; k0 < K; k0 += 32) {
    gload16(ga0, lA);
    gload16(ga1, lA + 4096);
    gload16(gb0, lB);
    gload16(gb1, lB + 4096);
    ga0 += 32; ga1 += 32; gb0 += 32; gb1 += 32;
    __syncthreads();
    bf16x8 af[4], bfr[4];
#pragma unroll
    for (int i = 0; i < 4; ++i)
      af[i] = *(const bf16x8*)(At + (wr * 64 + i * 16 + lr) * 32 + lk * 8);
#pragma unroll
    for (int j = 0; j < 4; ++j)
      bfr[j] = *(const bf16x8*)(Bt + (wc * 64 + j * 16 + lr) * 32 + lk * 8);
#pragma unroll
    for (int i = 0; i < 4; ++i) {
#pragma unroll
      for (int j = 0; j < 4; ++j) acc[i][j] = MFMA16(af[i], bfr[j], acc[i][j]);
    }
    __syncthreads();
  }

#pragma unroll
  for (int i = 0; i < 4; ++i) {
#pragma unroll
    for (int j = 0; j < 4; ++j) {
#pragma unroll
      for (int jj = 0; jj < 4; ++jj) {
        int row = bm0 + wr * 64 + i * 16 + lk * 4 + jj;
        int col = bn0 + wc * 64 + j * 16 + lr;
        C[(size_t)row * N + col] = (OutT)acc[i][j][jj];
      }
    }
  }
}

// ---------------- GEMM 256x256, 8-phase counted-vmcnt schedule (T2+T3+T4+T5) ----------------
// 8 waves (2M x 4N), per-wave 128x64 output. BK=64; iteration = 2 K-tiles (even->slot0, odd->slot1).
// LDS: A/B each [slot][half 128rows][64] bf16, XOR-swizzled 16B blocks. One half-tile staged per
// phase (2 x gload_lds). vmcnt(2) at phases 4 & 8 only; each phase's ds_reads are consumed by its
// own MFMA cluster, so LDS regions are dead before the overwriting stage 4+ phases later.
template <typename OutT>
__global__ __launch_bounds__(512, 2) void k_gemm256(const __bf16* __restrict__ A,
                                                    const __bf16* __restrict__ BT,
                                                    OutT* __restrict__ C,
                                                    int M, int N, int K) {
  __shared__ __align__(16) __bf16 Als[2][2][128 * 64];  // [slot][half][row*64]
  __shared__ __align__(16) __bf16 Bls[2][2][128 * 64];
  const int tid = threadIdx.x;
  const int l = tid & 63, w = tid >> 6;
  const int wm = w >> 2, wn = w & 3;
  const int wnh = wn >> 1, wnl = wn & 1;
  const int lr = l & 15, lk = l >> 4, lr7 = lr & 7;
  const int bm0 = blockIdx.y * 256, bn0 = blockIdx.x * 256;
  const int sr0 = w * 8 + (l >> 3);           // staging row within 64-row chunk
  const int sc0 = ((l & 7) ^ (l >> 3)) * 8;   // pre-swizzled global col (elems)
  const int xo0 = (lk ^ lr7) * 8;             // swizzled read offsets (elems)
  const int xo1 = ((4 + lk) ^ lr7) * 8;

#define STAGE_A(KT, H) do {                                                      \
    const __bf16* s_ = A + (size_t)(bm0 + (H) * 128 + sr0) * K + (KT) * 64 + sc0; \
    char* d_ = (char*)&Als[(KT) & 1][H][0] + w * 1024;                            \
    gload16(s_, d_);                                                              \
    gload16(s_ + (size_t)64 * K, d_ + 8192);                                      \
  } while (0)
#define STAGE_B(KT, H) do {                                                       \
    const __bf16* s_ = BT + (size_t)(bn0 + (H) * 128 + sr0) * K + (KT) * 64 + sc0; \
    char* d_ = (char*)&Bls[(KT) & 1][H][0] + w * 1024;                             \
    gload16(s_, d_);                                                               \
    gload16(s_ + (size_t)64 * K, d_ + 8192);                                       \
  } while (0)
#define LDA(SLOT, QM) do {                                                  \
    _Pragma("unroll") for (int f_ = 0; f_ < 4; ++f_) {                      \
      const __bf16* rp_ = &Als[SLOT][wm][0] + ((QM) * 64 + f_ * 16 + lr) * 64; \
      af[f_][0] = *(const bf16x8*)(rp_ + xo0);                              \
      af[f_][1] = *(const bf16x8*)(rp_ + xo1);                              \
    }                                                                       \
  } while (0)
#define LDB(SLOT, QN) do {                                                  \
    _Pragma("unroll") for (int g_ = 0; g_ < 2; ++g_) {                      \
      const __bf16* rp_ = &Bls[SLOT][wnh][0] + (wnl * 64 + (QN) * 32 + g_ * 16 + lr) * 64; \
      bq[QN][g_][0] = *(const bf16x8*)(rp_ + xo0);                          \
      bq[QN][g_][1] = *(const bf16x8*)(rp_ + xo1);                          \
    }                                                                       \
  } while (0)
#define MFMAQ(QM, QN) do {                                                  \
    __builtin_amdgcn_s_setprio(1);                                          \
    _Pragma("unroll") for (int f_ = 0; f_ < 4; ++f_) {                      \
      _Pragma("unroll") for (int g_ = 0; g_ < 2; ++g_) {                    \
        acc[(QM) * 4 + f_][(QN) * 2 + g_] =                                 \
            MFMA16(af[f_][0], bq[QN][g_][0], acc[(QM) * 4 + f_][(QN) * 2 + g_]); \
        acc[(QM) * 4 + f_][(QN) * 2 + g_] =                                 \
            MFMA16(af[f_][1], bq[QN][g_][1], acc[(QM) * 4 + f_][(QN) * 2 + g_]); \
      }                                                                     \
    }                                                                       \
    __builtin_amdgcn_s_setprio(0);                                          \
  } while (0)
#define BAR() asm volatile("s_barrier" ::: "memory")
#define VMCNT2() asm volatile("s_waitcnt vmcnt(2)" ::: "memory")
#define VMCNT0() asm volatile("s_waitcnt vmcnt(0)" ::: "memory")

  f32x4 acc[8][4];
  const f32x4 fz = {0.f, 0.f, 0.f, 0.f};
#pragma unroll
  for (int m = 0; m < 8; ++m) {
#pragma unroll
    for (int n = 0; n < 4; ++n) acc[m][n] = fz;
  }
  bf16x8 af[4][2], bq[2][2][2];

  // prologue: slot0 (kt0) fully + A(kt1) half0; leave A(kt1)h0 in flight (= steady-state P8 stage)
  STAGE_A(0, 0); STAGE_A(0, 1); STAGE_B(0, 0); STAGE_B(0, 1); STAGE_A(1, 0);
  VMCNT2();
  BAR();

  const int NT = K >> 7;
#pragma unroll 1
  for (int t = 0; t < NT; ++t) {
    const int k1 = 2 * t + 1, k2 = 2 * t + 2, k3 = 2 * t + 3;
    const bool last = (t == NT - 1);
    // P1: reads kt0 A(qm0), B(qn0)  [gated by prev P8 vmcnt+bar]
    LDA(0, 0); LDB(0, 0);
    STAGE_A(k1, 1);
    BAR(); MFMAQ(0, 0); BAR();
    // P2
    LDB(0, 1);
    STAGE_B(k1, 0);
    BAR(); MFMAQ(0, 1); BAR();
    // P3
    LDA(0, 1);
    STAGE_B(k1, 1);
    BAR(); MFMAQ(1, 1); BAR();
    // P4: vmcnt completes {prevP8, P1, P2, P3} -> kt1 fully staged for P5..P7 reads
    if (!last) { STAGE_A(k2, 0); VMCNT2(); } else { VMCNT0(); }
    BAR(); MFMAQ(1, 0); BAR();
    // P5: reads kt1 A(qm0), B(qn0)
    LDA(1, 0); LDB(1, 0);
    if (!last) STAGE_A(k2, 1);
    BAR(); MFMAQ(0, 0); BAR();
    // P6
    LDB(1, 1);
    if (!last) STAGE_B(k2, 0);
    BAR(); MFMAQ(0, 1); BAR();
    // P7
    LDA(1, 1);
    if (!last) STAGE_B(k2, 1);
    BAR(); MFMAQ(1, 1); BAR();
    // P8: vmcnt completes {P4..P7} -> slot0 (kt2) staged for next iter's P1 reads
    if (!last) { STAGE_A(k3, 0); VMCNT2(); }
    BAR(); MFMAQ(1, 0); BAR();
  }

  // epilogue
#pragma unroll
  for (int m = 0; m < 8; ++m) {
    const int row = bm0 + wm * 128 + (m >> 2) * 64 + (m & 3) * 16 + lk * 4;
#pragma unroll
    for (int n = 0; n < 4; ++n) {
      const int col = bn0 + wn * 64 + (n >> 1) * 32 + (n & 1) * 16 + lr;
#pragma unroll
      for (int jj = 0; jj < 4; ++jj)
        C[(size_t)(row + jj) * N + col] = (OutT)acc[m][n][jj];
    }
  }
#undef STAGE_A
#undef STAGE_B
#undef LDA
#undef LDB
#undef MFMAQ
#undef BAR
#undef VMCNT2
#undef VMCNT0
}

// ---------------- causal flash attention (swapped QK^T, in-register softmax) ----------------
__global__ __launch_bounds__(256, 2) void k_attn(const __bf16* __restrict__ qkv,
                                                 const __bf16* __restrict__ vt,
                                                 __bf16* __restrict__ ctx) {
  const int p = blockIdx.x, h = blockIdx.y, b = blockIdx.z;
  const int l = threadIdx.x & 63, w = threadIdx.x >> 6;
  const int q = l & 31, hi = l >> 5, l7 = l & 7;

  __shared__ __align__(16) __bf16 KVs[2][2][64 * 64];  // [buf][K|V^T][...] 32 KB

  const int srow = w * 8 + (l >> 3);
  const int scol = ((l & 7) ^ (l >> 3)) * 8;

  const __bf16* gK = qkv + (size_t)(b * 2048) * 3072 + 1024 + h * 64;  // stride 3072
  const __bf16* gV = vt + (size_t)((b * 16 + h) * 64) * 2048;          // stride 2048

  const float NEG = -1e30f;

#pragma unroll 1
  for (int ti = 0; ti < 2; ++ti) {
    const int qb = (ti == 0) ? (15 - p) : p;
    const int q0w = qb * 128 + w * 32;
    const int qg = q0w + q;
    const int nkv = 2 * qb + 2;
    const int kvlast = (q0w + 31) >> 6;

    const __bf16* qp = qkv + (size_t)(b * 2048 + qg) * 3072 + h * 64 + hi * 8;
    bf16x8 qf[4];
#pragma unroll
    for (int d0 = 0; d0 < 4; ++d0) qf[d0] = *(const bf16x8*)(qp + d0 * 16);

    float m_run = NEG, lsum = 0.f;
    f32x16 o0 = (f32x16)(0.0f), o1 = (f32x16)(0.0f);

#pragma unroll
    for (int i = 0; i < 2; ++i) {
      gload16(gK + (size_t)(i * 32 + srow) * 3072 + scol, (char*)&KVs[0][0][0] + i * 4096 + w * 1024);
      gload16(gV + (size_t)(i * 32 + srow) * 2048 + scol, (char*)&KVs[0][1][0] + i * 4096 + w * 1024);
    }
    __syncthreads();

#pragma unroll 1
    for (int kvt = 0; kvt < nkv; ++kvt) {
      const int cur = kvt & 1;
      const int kv0 = kvt * 64;
      if (kvt + 1 < nkv) {
        const int nk0 = kv0 + 64;
#pragma unroll
        for (int i = 0; i < 2; ++i) {
          gload16(gK + (size_t)(nk0 + i * 32 + srow) * 3072 + scol,
                  (char*)&KVs[cur ^ 1][0][0] + i * 4096 + w * 1024);
          gload16(gV + (size_t)(i * 32 + srow) * 2048 + nk0 + scol,
                  (char*)&KVs[cur ^ 1][1][0] + i * 4096 + w * 1024);
        }
      }
      if (kvt <= kvlast) {
        const __bf16* Kb = &KVs[cur][0][0];
        const __bf16* Vb = &KVs[cur][1][0];

        f32x16 s0 = (f32x16)(0.0f), s1 = (f32x16)(0.0f);
#pragma unroll
        for (int d0 = 0; d0 < 4; ++d0) {
          bf16x8 k0 = *(const bf16x8*)(Kb + (size_t)q * 64 + (((d0 * 2 + hi) ^ l7) * 8));
          bf16x8 k1 = *(const bf16x8*)(Kb + (size_t)(32 + q) * 64 + (((d0 * 2 + hi) ^ l7) * 8));
          s0 = MFMA32(k0, qf[d0], s0);
          s1 = MFMA32(k1, qf[d0], s1);
        }

        if (kvt == kvlast) {
#pragma unroll
          for (int r = 0; r < 16; ++r) {
            const int kl = (r & 3) + 8 * (r >> 2) + 4 * hi;
            if (kv0 + kl > qg) s0[r] = NEG;
            if (kv0 + 32 + kl > qg) s1[r] = NEG;
          }
        }

        float t[8];
#pragma unroll
        for (int i = 0; i < 8; ++i)
          t[i] = fmaxf(fmaxf(s0[i], s0[i + 8]), fmaxf(s1[i], s1[i + 8]));
#pragma unroll
        for (int i = 0; i < 4; ++i) t[i] = fmaxf(t[i], t[i + 4]);
        float mt = fmaxf(fmaxf(t[0], t[1]), fmaxf(t[2], t[3]));
        mt = fmaxf(mt, __shfl_xor(mt, 32));

        if (!__all(mt - m_run <= 8.0f)) {
          const float al = __expf(m_run - mt);
          lsum *= al;
#pragma unroll
          for (int r = 0; r < 16; ++r) { o0[r] *= al; o1[r] *= al; }
          m_run = mt;
        }

#pragma unroll
        for (int r = 0; r < 16; ++r) {
          s0[r] = __expf(s0[r] - m_run);
          s1[r] = __expf(s1[r] - m_run);
        }
        float sa[8];
#pragma unroll
        for (int i = 0; i < 8; ++i) sa[i] = (s0[i] + s0[i + 8]) + (s1[i] + s1[i + 8]);
#pragma unroll
        for (int i = 0; i < 4; ++i) sa[i] += sa[i + 4];
        float sm = (sa[0] + sa[1]) + (sa[2] + sa[3]);
        sm += __shfl_xor(sm, 32);
        lsum += sm;

        uint32_t c0[8], c1[8];
#pragma unroll
        for (int j = 0; j < 8; ++j) {
          c0[j] = packbf(s0[2 * j], s0[2 * j + 1]);
          c1[j] = packbf(s1[2 * j], s1[2 * j + 1]);
        }
        u32x4 pk[4];
        {
          u32x2 r0 = __builtin_amdgcn_permlane32_swap(c0[0], c0[2], false, false);
          u32x2 r1 = __builtin_amdgcn_permlane32_swap(c0[1], c0[3], false, false);
          u32x2 r2 = __builtin_amdgcn_permlane32_swap(c0[4], c0[6], false, false);
          u32x2 r3 = __builtin_amdgcn_permlane32_swap(c0[5], c0[7], false, false);
          pk[0].x = r0.x; pk[0].y = r1.x; pk[0].z = r0.y; pk[0].w = r1.y;
          pk[1].x = r2.x; pk[1].y = r3.x; pk[1].z = r2.y; pk[1].w = r3.y;
          u32x2 r4 = __builtin_amdgcn_permlane32_swap(c1[0], c1[2], false, false);
          u32x2 r5 = __builtin_amdgcn_permlane32_swap(c1[1], c1[3], false, false);
          u32x2 r6 = __builtin_amdgcn_permlane32_swap(c1[4], c1[6], false, false);
          u32x2 r7 = __builtin_amdgcn_permlane32_swap(c1[5], c1[7], false, false);
          pk[2].x = r4.x; pk[2].y = r5.x; pk[2].z = r4.y; pk[2].w = r5.y;
          pk[3].x = r6.x; pk[3].y = r7.x; pk[3].z = r6.y; pk[3].w = r7.y;
        }
        bf16x8 pf[4];
#pragma unroll
        for (int kc = 0; kc < 4; ++kc) pf[kc] = __builtin_bit_cast(bf16x8, pk[kc]);

#pragma unroll
        for (int kc = 0; kc < 4; ++kc) {
          bf16x8 vf0 = *(const bf16x8*)(Vb + (size_t)q * 64 + (((kc * 2 + hi) ^ l7) * 8));
          o0 = MFMA32(vf0, pf[kc], o0);
        }
#pragma unroll
        for (int kc = 0; kc < 4; ++kc) {
          bf16x8 vf1 = *(const bf16x8*)(Vb + (size_t)(32 + q) * 64 + (((kc * 2 + hi) ^ l7) * 8));
          o1 = MFMA32(vf1, pf[kc], o1);
        }
      }
      __syncthreads();
    }

    const float inv = 1.0f / lsum;
    __bf16* Ol = &KVs[0][0][0];
#pragma unroll
    for (int r = 0; r < 16; ++r) {
      const int d = (r & 3) + 8 * (r >> 2) + 4 * hi;
      Ol[(w * 32 + q) * 72 + d]      = (__bf16)(o0[r] * inv);
      Ol[(w * 32 + q) * 72 + 32 + d] = (__bf16)(o1[r] * inv);
    }
    __syncthreads();
    {
      const int row = threadIdx.x >> 1, half = threadIdx.x & 1;
      const __bf16* src = Ol + row * 72 + half * 32;
      __bf16* dst = ctx + (size_t)(b * 2048 + qb * 128 + row) * 1024 + h * 64 + half * 32;
#pragma unroll
      for (int i = 0; i < 4; ++i)
        *(bf16x8*)(dst + i * 8) = *(const bf16x8*)(src + i * 8);
    }
    __syncthreads();
  }
}

extern "C" void kernel_launch(void* const* d_in, const int* in_sizes, int n_in,
                              void* d_out, int out_size, void* d_ws, size_t ws_size,
                              hipStream_t stream) {
  const float* x    = (const float*)d_in[0];   // [8192,1024]
  const float* wqkv = (const float*)d_in[1];   // [1024,3072]
  const float* wout = (const float*)d_in[2];   // [1024,1024]
  float* out = (float*)d_out;                  // [8192,1024]

  char* ws = (char*)d_ws;
  __bf16* xb    = (__bf16*)(ws);
  __bf16* wqkvT = (__bf16*)(ws + 16777216);
  __bf16* woutT = (__bf16*)(ws + 23068672);
  __bf16* qkvb  = (__bf16*)(ws + 25165824);
  __bf16* vtb   = (__bf16*)(ws + 75497472);
  __bf16* ctx   = (__bf16*)(ws + 92274688);

  k_f32_to_bf16<<<2048, 256, 0, stream>>>(x, xb, 8192 * 1024);
  k_transpose_f32_bf16<<<dim3(48, 16), 256, 0, stream>>>(wqkv, wqkvT, 1024, 3072, 0.125f, 1024);
  k_transpose_f32_bf16<<<dim3(16, 16), 256, 0, stream>>>(wout, woutT, 1024, 1024, 1.0f, 0);
  k_gemm256<__bf16><<<dim3(12, 32), 512, 0, stream>>>(xb, wqkvT, qkvb, 8192, 3072, 1024);
  k_vtrans<<<dim3(32, 16, 4), 256, 0, stream>>>(qkvb, vtb);
  k_attn<<<dim3(8, 16, 4), 256, 0, stream>>>(qkvb, vtb, ctx);
  k_gemm_bt<float><<<dim3(8, 64), 256, 0, stream>>>(ctx, woutT, out, 8192, 1024, 1024);
}